// Round 4
// baseline (6857.788 us; speedup 1.0000x reference)
//
#include <hip/hip_runtime.h>

typedef _Float16 f16;
typedef _Float16 f16x8 __attribute__((ext_vector_type(8)));
typedef float    f32x4 __attribute__((ext_vector_type(4)));
typedef unsigned int uint32;

#define DEVI static __device__ __forceinline__

constexpr int BATCH = 64;
constexpr int TT    = 400;
constexpr int DIN   = 1024;    // layer input width (== 2*HH)
constexpr int HH    = 512;
constexpr int M6    = 6*HH;    // 3072: 6 gates, one direction
constexpr int NN    = 2*M6;    // 6144
constexpr int MM    = BATCH*TT;
constexpr int TC    = 50;      // timesteps per chunk
constexpr int NCH   = TT/TC;   // 8 chunks
constexpr int HR    = TC+1;    // 51 h-ring slots (max intra-chunk skew 49 < 51)
constexpr int MCH   = TC*BATCH;// 3200 rows per chunk sub-GEMM

DEVI float sigm(float x)   { return __fdividef(1.f, 1.f + __expf(-x)); }
DEVI float tanh_f(float x) { return 1.f - __fdividef(2.f, 1.f + __expf(2.f*x)); }

DEVI void g2lds16(const void* g, void* l) {
    __builtin_amdgcn_global_load_lds(
        (const __attribute__((address_space(1))) uint32*)g,
        (__attribute__((address_space(3))) uint32*)l, 16, 0, 0);
}

DEVI void waitv0() {
    asm volatile("s_waitcnt vmcnt(0)" ::: "memory");
    __builtin_amdgcn_sched_barrier(0);   // rule #18
}
DEVI float f16lo(uint32 u){ union{unsigned short s; f16 h;} c; c.s=(unsigned short)(u&0xffffu); return (float)c.h; }
DEVI float f16hi(uint32 u){ union{unsigned short s; f16 h;} c; c.s=(unsigned short)(u>>16);     return (float)c.h; }

// ---------------- x: (B,T,D) f32 -> (T,B,D) f16 ----------------
__global__ __launch_bounds__(256) void cvt_x(const float* __restrict__ x, f16* __restrict__ xb) {
    int g  = blockIdx.x*256 + threadIdx.x;
    int d4 = g & 255;
    int bt = g >> 8;
    int b  = bt / TT, t = bt - b*TT;
    float4 v = *reinterpret_cast<const float4*>(x + (size_t)bt*DIN + d4*4);
    union { f16 h[4]; uint2 u; } pk;
    pk.h[0]=(f16)v.x; pk.h[1]=(f16)v.y; pk.h[2]=(f16)v.z; pk.h[3]=(f16)v.w;
    *reinterpret_cast<uint2*>(xb + (size_t)(t*BATCH + b)*DIN + d4*4) = pk.u;
}

// ---------------- generic f32 -> f16 ----------------
__global__ __launch_bounds__(256) void cvt_w(const float* __restrict__ s, f16* __restrict__ d, int n4) {
    int g = blockIdx.x*256 + threadIdx.x;
    if (g >= n4) return;
    float4 v = *reinterpret_cast<const float4*>(s + (size_t)g*4);
    union { f16 h[4]; uint2 u; } pk;
    pk.h[0]=(f16)v.x; pk.h[1]=(f16)v.y; pk.h[2]=(f16)v.z; pk.h[3]=(f16)v.w;
    *reinterpret_cast<uint2*>(d + (size_t)g*4) = pk.u;
}

// ---------------- chunk GEMM: C[m, j*6+g] = sum_k A[amap(m),k]*Bt[g*512+j,k] ----------------
// amap(m) = arow0 + (m>>6)*astep + (m&63); pi output is GATE-INTERLEAVED per column.
__global__ __launch_bounds__(256) void gemm_nt(const f16* __restrict__ A, const f16* __restrict__ Bt,
                                               f16* __restrict__ C, int M, int N, int K,
                                               int arow0, int astep) {
    __shared__ f16 As[128*64];
    __shared__ f16 Bs[128*64];
    const int nbm = M >> 7;
    const int GM  = 8;
    int g   = blockIdx.x;
    int bpg = GM * nbm;
    int grp = g / bpg, r = g - grp*bpg;
    int bn  = grp*GM + (r & (GM-1));
    int bm  = r >> 3;
    const int tid  = threadIdx.x;
    const int lane = tid & 63;
    const int w    = tid >> 6;
    const int wm   = w >> 1, wn = w & 1;

    f32x4 acc[4][4];
    #pragma unroll
    for (int i=0;i<4;i++)
        #pragma unroll
        for (int j=0;j<4;j++)
            acc[i][j] = f32x4{0.f,0.f,0.f,0.f};

    int arow[4];
    #pragma unroll
    for (int r4=0;r4<4;r4++) {
        int m = bm*128 + (tid>>3) + r4*32;
        arow[r4] = arow0 + (m>>6)*astep + (m&63);
    }
    const int kcol = (tid&7)*8;
    const f16* bptr = Bt + (size_t)(bn*128 + (tid>>3))*K + kcol;
    char* asb = (char*)As;
    char* bsb = (char*)Bs;

    for (int kt = 0; kt < K; kt += 64) {
        #pragma unroll
        for (int r4 = 0; r4 < 4; ++r4) {
            g2lds16(A + (size_t)arow[r4]*K + kt + kcol, asb + r4*4096 + w*1024);
            g2lds16(bptr + (size_t)r4*32*K + kt,        bsb + r4*4096 + w*1024);
        }
        __syncthreads();
        #pragma unroll
        for (int kk = 0; kk < 64; kk += 32) {
            f16x8 af[4], bf[4];
            const int kof = kk + (lane>>4)*8;
            #pragma unroll
            for (int i=0;i<4;i++)
                af[i] = *reinterpret_cast<const f16x8*>(&As[(wm*64 + i*16 + (lane&15))*64 + kof]);
            #pragma unroll
            for (int j=0;j<4;j++)
                bf[j] = *reinterpret_cast<const f16x8*>(&Bs[(wn*64 + j*16 + (lane&15))*64 + kof]);
            #pragma unroll
            for (int i=0;i<4;i++)
                #pragma unroll
                for (int j=0;j<4;j++)
                    acc[i][j] = __builtin_amdgcn_mfma_f32_16x16x32_f16(af[i], bf[j], acc[i][j], 0, 0, 0);
        }
        __syncthreads();
    }
    #pragma unroll
    for (int i=0;i<4;i++) {
        #pragma unroll
        for (int j=0;j<4;j++) {
            int row0 = bm*128 + wm*64 + i*16 + (lane>>4)*4;
            int col  = bn*128 + wn*64 + j*16 + (lane&15);
            int gg   = col >> 9, jj = col & 511;     // gate-interleave remap
            #pragma unroll
            for (int q=0;q<4;q++)
                C[(size_t)(row0+q)*N + jj*6 + gg] = (f16)acc[i][j][q];
        }
    }
}

// ---------------- persistent bidirectional LSTM scan, one 50-step chunk ----------------
// 64 WGs x 256 thr; WGs 0..31 fwd, 32..63 bwd; each WG owns 16 h-cols (Ws in LDS,
// XOR-swizzled). PER-WAVE protocol: wave w of producer p only feeds wave w of
// consumers (af rows = w*16+jl), so flags are [dir][ts][w][32] and the step loop has
// NO __syncthreads. h element-coherent via sc0 sc1; ordering by explicit vmcnt(0).
__global__ __launch_bounds__(256) void lstm_scan(
    const f16* __restrict__ piF,   // [TC*B][512][6] fwd pi chunk (gate-interleaved)
    const f16* __restrict__ piB,   // same, bwd
    const f16* __restrict__ Wsl,   // [2][5*HH][HH] this layer
    const float* __restrict__ bsl, // [2][5*HH] this layer
    const int* __restrict__ lens,  // [B]
    f16* __restrict__ hring,       // [2][HR][B][HH]
    int* __restrict__ flags,       // [2][TT][4][32] this layer (pre-zeroed)
    f16* __restrict__ y16,         // layer0 out: (T,B,2H) f16
    float* __restrict__ y32,       // layer1 out: d_out seq (B,T,2H) f32
    float* __restrict__ cbuf,      // [2][B][HH] f32 c-state carry
    int s0, int first, int last)
{
    __shared__ f16 wlds[80*512];   // 80 KB, rows rr = gate*16 + jcol, XOR-swizzled
    const int tid  = threadIdx.x;
    const int lane = tid & 63;
    const int w    = tid >> 6;
    const int dir  = blockIdx.x >> 5;
    const int wgd  = blockIdx.x & 31;
    const int j0   = wgd*16;
    const int jl   = lane & 15;
    const int rq   = lane >> 4;

    {   // stage Ws slice (byte ^= (row&7)<<4)
        const f16* wbase = Wsl + (size_t)dir*5*HH*HH;
        for (int c = tid; c < 80*64; c += 256) {
            int rr = c >> 6, cc = c & 63;
            int grow = (rr>>4)*HH + j0 + (rr&15);
            uint4 v = *reinterpret_cast<const uint4*>(wbase + (size_t)grow*HH + cc*8);
            *reinterpret_cast<uint4*>((char*)wlds + rr*1024 + ((cc*16) ^ ((rr&7)<<4))) = v;
        }
    }

    int   lenr[4];
    float bias[5];
    #pragma unroll
    for (int r2=0;r2<4;r2++) lenr[r2] = lens[w*16 + rq*4 + r2];
    #pragma unroll
    for (int g2=0;g2<5;g2++) bias[g2] = bsl[dir*5*HH + g2*HH + j0 + jl];

    f16* hD  = hring + (size_t)dir*HR*BATCH*HH;
    int* flD = flags + dir*TT*4*32;
    const f16* piD = dir ? piB : piF;

    float cst[4], holdf[4];
    {
        const f16* h0 = hD + (size_t)(s0 % HR)*BATCH*HH;
        #pragma unroll
        for (int r2=0;r2<4;r2++) {
            int b = w*16 + rq*4 + r2;
            cst[r2]   = first ? 0.f : cbuf[dir*BATCH*HH + b*HH + j0 + jl];
            holdf[r2] = (float)h0[(size_t)b*HH + j0 + jl];
        }
    }

    __syncthreads();   // wlds ready; no further intra-WG sync

    for (int ts = s0; ts < s0 + TC; ++ts) {
        const int tau = dir ? (TT-1-ts) : ts;

        // pi loads (cached, contiguous 12B per row; overlap the poll)
        uint32 praw[4][3];
        {
            const char* pib = (const char*)piD + (size_t)(ts - s0)*BATCH*M6*2;
            #pragma unroll
            for (int r2=0;r2<4;r2++) {
                int b = w*16 + rq*4 + r2;
                const uint32* pp = (const uint32*)(pib + ((size_t)b*M6 + (j0+jl)*6)*2);
                praw[r2][0] = pp[0]; praw[r2][1] = pp[1]; praw[r2][2] = pp[2];
            }
        }

        // per-wave wait: all 32 producers' wave-w slices of step ts-1
        if (ts > s0) {
            const int* fl = flD + ((ts-1)*4 + w)*32 + (lane & 31);
            int iters = 0;
            for (;;) {
                int v;
                asm volatile("global_load_dword %0, %1, off sc0 sc1\n\t"
                             "s_waitcnt vmcnt(0)"
                             : "=v"(v) : "v"(fl) : "memory");
                if (__all(v != 0)) break;
                if (++iters > 400000) break;   // hang guard
            }
        }
        __builtin_amdgcn_sched_barrier(0);

        // coherent h A-fragment loads: one base + immediate offsets
        const f16* hb = hD + (size_t)(ts % HR)*BATCH*HH + (size_t)(w*16 + jl)*HH + rq*8;
        f16x8 af[16];
        #define LDAF(K, OFF) asm volatile("global_load_dwordx4 %0, %1, off offset:" #OFF " sc0 sc1" \
                                          : "=v"(af[K]) : "v"(hb) : "memory");
        LDAF(0,0)  LDAF(1,64)  LDAF(2,128)  LDAF(3,192)
        LDAF(4,256) LDAF(5,320) LDAF(6,384) LDAF(7,448)
        LDAF(8,512) LDAF(9,576) LDAF(10,640) LDAF(11,704)
        LDAF(12,768) LDAF(13,832) LDAF(14,896) LDAF(15,960)
        #undef LDAF
        waitv0();

        // ps = h @ Ws^T : bias pre-loaded into accumulators
        f32x4 accP[5];
        #pragma unroll
        for (int g2=0;g2<5;g2++) accP[g2] = f32x4{bias[g2],bias[g2],bias[g2],bias[g2]};
        #pragma unroll
        for (int ks=0; ks<16; ++ks) {
            const int kbyte = ks*64 + rq*16;
            #pragma unroll
            for (int g2=0; g2<5; ++g2) {
                const int rr = g2*16 + jl;
                f16x8 bfr = *reinterpret_cast<const f16x8*>((char*)wlds + rr*1024 + (kbyte ^ ((rr&7)<<4)));
                accP[g2] = __builtin_amdgcn_mfma_f32_16x16x32_f16(af[ks], bfr, accP[g2], 0, 0, 0);
            }
        }

        // gates (fp32), highway, masking; hold carried in registers
        unsigned short hnewb[4];
        float yv[4];
        #pragma unroll
        for (int r2=0;r2<4;r2++) {
            float p0=f16lo(praw[r2][0]), p1=f16hi(praw[r2][0]);
            float p2=f16lo(praw[r2][1]), p3=f16hi(praw[r2][1]);
            float p4=f16lo(praw[r2][2]), p5=f16hi(praw[r2][2]);
            float ig = sigm  (accP[0][r2] + p0);
            float fg = sigm  (accP[1][r2] + p1);
            float mg = tanh_f(accP[2][r2] + p2);
            float og = sigm  (accP[3][r2] + p3);
            float hw = sigm  (accP[4][r2] + p4);
            float cn = ig*mg + fg*cst[r2];
            float op = og * tanh_f(cn);
            float ov = hw*op + (1.f - hw)*p5;
            bool act = (tau < lenr[r2]);
            float h2 = act ? ov : holdf[r2];
            cst[r2]  = act ? cn : cst[r2];
            yv[r2]   = act ? ov : 0.f;
            holdf[r2] = h2;
            union { unsigned short s; f16 h; } nv; nv.h = (f16)h2;
            hnewb[r2] = nv.s;
        }

        // publish wave-w h slice, drain, signal per-wave flag
        {
            f16* hsb = hD + (size_t)((ts+1) % HR)*BATCH*HH + (size_t)(w*16 + rq*4)*HH + j0 + jl;
            #define STH(R, OFF) { unsigned int vv = hnewb[R]; \
                asm volatile("global_store_short %1, %0, off offset:" #OFF " sc0 sc1" \
                             :: "v"(vv), "v"(hsb) : "memory"); }
            STH(0,0) STH(1,1024) STH(2,2048) STH(3,3072)
            #undef STH
        }
        waitv0();
        if (lane == 0) {
            int* fp = flD + (ts*4 + w)*32 + wgd;
            unsigned int one = 1;
            asm volatile("global_store_dword %1, %0, off sc0 sc1"
                         :: "v"(one), "v"(fp) : "memory");
        }

        // y writes off the critical path (cached)
        if (!last) {
            #pragma unroll
            for (int r2=0;r2<4;r2++) {
                int b = w*16 + rq*4 + r2;
                y16[(size_t)(tau*BATCH + b)*DIN + dir*HH + j0 + jl] = (f16)yv[r2];
            }
        } else {
            #pragma unroll
            for (int r2=0;r2<4;r2++) {
                int b = w*16 + rq*4 + r2;
                y32[(size_t)(b*TT + tau)*DIN + dir*HH + j0 + jl] = yv[r2];
            }
        }
    }

    #pragma unroll
    for (int r2=0;r2<4;r2++) {
        int b = w*16 + rq*4 + r2;
        cbuf[dir*BATCH*HH + b*HH + j0 + jl] = cst[r2];
    }
}

// ---------------- finalize: h[T] (ring slot), c -> d_out (B,2H) f32 ----------------
__global__ __launch_bounds__(256) void finalize(const f16* __restrict__ hring,
                                                const float* __restrict__ cbuf,
                                                float* __restrict__ outh,
                                                float* __restrict__ outc, int slot) {
    int i = blockIdx.x*256 + threadIdx.x;
    int dir = i >> 15, rem = i & 32767;
    int b = rem >> 9, j = rem & 511;
    outh[(size_t)b*(2*HH) + dir*HH + j] =
        (float)hring[(size_t)dir*HR*BATCH*HH + (size_t)slot*BATCH*HH + (size_t)b*HH + j];
    outc[(size_t)b*(2*HH) + dir*HH + j] = cbuf[dir*BATCH*HH + b*HH + j];
}

extern "C" void kernel_launch(void* const* d_in, const int* in_sizes, int n_in,
                              void* d_out, int out_size, void* d_ws, size_t ws_size,
                              hipStream_t stream) {
    (void)in_sizes; (void)n_in; (void)out_size; (void)ws_size;
    const float* x    = (const float*)d_in[0];
    const int*   lens = (const int*)  d_in[1];
    const float* Wi   = (const float*)d_in[2];
    const float* Ws   = (const float*)d_in[3];
    const float* bs   = (const float*)d_in[4];
    float* out = (float*)d_out;

    char* ws = (char*)d_ws;
    size_t off = 0;
    auto alloc = [&](size_t bytes) -> char* {
        char* p = ws + off;
        off += (bytes + 1023) & ~(size_t)1023;
        return p;
    };
    f16* xb0   = (f16*)alloc((size_t)MM*DIN*2);        // 52.4 MB
    f16* xb1   = (f16*)alloc((size_t)MM*DIN*2);        // 52.4 MB
    f16* wi16  = (f16*)alloc((size_t)NN*DIN*2);        // 12.6 MB
    f16* ws16  = (f16*)alloc((size_t)2*2*5*HH*HH*2);   // 10.5 MB
    f16* piF   = (f16*)alloc((size_t)MCH*M6*2);        // 19.7 MB
    f16* piB   = (f16*)alloc((size_t)MCH*M6*2);        // 19.7 MB
    f16* hring = (f16*)alloc((size_t)2*HR*BATCH*HH*2); //  6.7 MB
    float* cbuf= (float*)alloc((size_t)2*BATCH*HH*4);  //  0.3 MB
    int* flags = (int*)alloc((size_t)2*2*TT*4*32*4);   //  0.8 MB  per-wave flags
    // total ~176 MB

    (void)hipMemsetAsync(flags, 0, (size_t)2*2*TT*4*32*4, stream);
    (void)hipMemsetAsync(hring, 0, (size_t)BATCH*HH*2, stream);
    (void)hipMemsetAsync((char*)hring + (size_t)HR*BATCH*HH*2, 0, (size_t)BATCH*HH*2, stream);

    cvt_x<<<MM*DIN/4/256, 256, 0, stream>>>(x, xb0);
    cvt_w<<<(2*2*5*HH*HH/4)/256, 256, 0, stream>>>(Ws, ws16, 2*2*5*HH*HH/4);

    float* outh = out + (size_t)MM*DIN;
    float* outc = outh + (size_t)2*BATCH*2*HH;

    for (int layer = 0; layer < 2; ++layer) {
        if (layer == 1) {
            (void)hipMemsetAsync(hring, 0, (size_t)BATCH*HH*2, stream);
            (void)hipMemsetAsync((char*)hring + (size_t)HR*BATCH*HH*2, 0, (size_t)BATCH*HH*2, stream);
        }
        cvt_w<<<(NN*DIN/4)/256, 256, 0, stream>>>(Wi + (size_t)layer*NN*DIN, wi16, NN*DIN/4);
        const f16* Axb = layer ? xb1 : xb0;
        for (int k = 0; k < NCH; ++k) {
            int s0 = k*TC;
            gemm_nt<<<(MCH/128)*(M6/128), 256, 0, stream>>>(Axb, wi16,                  piF, MCH, M6, DIN, s0*64, 64);
            gemm_nt<<<(MCH/128)*(M6/128), 256, 0, stream>>>(Axb, wi16 + (size_t)M6*DIN, piB, MCH, M6, DIN, (TT-1-s0)*64, -64);
            lstm_scan<<<64, 256, 0, stream>>>(piF, piB,
                ws16 + (size_t)layer*2*5*HH*HH,
                bs   + (size_t)layer*2*5*HH,
                lens, hring,
                flags + (size_t)layer*2*TT*4*32,
                xb1, out, cbuf, s0, k==0, layer);
        }
        finalize<<<(2*BATCH*HH)/256, 256, 0, stream>>>(hring, cbuf,
            outh + (size_t)layer*BATCH*2*HH,
            outc + (size_t)layer*BATCH*2*HH, TT % HR);
    }
}